// Round 9
// baseline (145.789 us; speedup 1.0000x reference)
//
#include <hip/hip_runtime.h>
#include <hip/hip_bf16.h>
#include <hip/hip_fp8.h>
#include <stdint.h>

#define BS   16384
#define NC   2000
#define NCP  2048            // padded N (wn zero-filled rows 2000..2047)
#define EMB  512
#define NAUX 5
#define NCHUNK 32            // partial chunks per row: nTile*4 + wvN (64 cols each)
#define GBLK 4096            // gather_fin blocks (4 rows each)

typedef __bf16 bf16x8 __attribute__((ext_vector_type(8)));
typedef float  f32x4  __attribute__((ext_vector_type(4)));

// ---------------------------------------------------------------------------
// Kernel 1 (v2): row-normalize; one WAVE per row, fully coalesced.
// ---------------------------------------------------------------------------
__global__ __launch_bounds__(256) void norm_kernel(
    const float* __restrict__ feat, const float* __restrict__ wemb,
    unsigned char* __restrict__ fn8, unsigned char* __restrict__ wn8,
    __bf16* __restrict__ fnb, __bf16* __restrict__ wnb)
{
    const int lane = threadIdx.x & 63;
    const int wv   = threadIdx.x >> 6;
    const int row  = blockIdx.x * 4 + wv;        // 0..18431

    if (row >= BS + NC) {                        // pad rows -> zeros
        const int pr = row - BS;
        *(unsigned*)(wn8 + (size_t)pr * EMB + lane * 4)       = 0u;
        *(unsigned*)(wn8 + (size_t)pr * EMB + 256 + lane * 4) = 0u;
        ushort4 z = {0, 0, 0, 0};
        ((ushort4*)(wnb + (size_t)pr * EMB))[lane]      = z;
        ((ushort4*)(wnb + (size_t)pr * EMB))[64 + lane] = z;
        return;
    }
    const float* src;
    unsigned char* dst8;
    __bf16* dstb;
    if (row < BS) { src = feat + (size_t)row * EMB;
                    dst8 = fn8 + (size_t)row * EMB;        dstb = fnb + (size_t)row * EMB; }
    else          { src = wemb + (size_t)(row - BS) * EMB;
                    dst8 = wn8 + (size_t)(row - BS) * EMB; dstb = wnb + (size_t)(row - BS) * EMB; }

    const float4* s4 = (const float4*)src;
    float4 x = s4[lane];                         // cols 4*lane   .. +3
    float4 y = s4[64 + lane];                    // cols 256+4*lane .. +3

    float ss = x.x * x.x + x.y * x.y + x.z * x.z + x.w * x.w
             + y.x * y.x + y.y * y.y + y.z * y.z + y.w * y.w;
    #pragma unroll
    for (int m = 1; m < 64; m <<= 1) ss += __shfl_xor(ss, m, 64);
    const float scale = 1.0f / fmaxf(sqrtf(ss), 1e-12f);

    float v[8];
    v[0] = x.x * scale; v[1] = x.y * scale; v[2] = x.z * scale; v[3] = x.w * scale;
    v[4] = y.x * scale; v[5] = y.y * scale; v[6] = y.z * scale; v[7] = y.w * scale;

    // bf16 copy (two 8 B coalesced stores)
    __bf16 b[8];
    #pragma unroll
    for (int j = 0; j < 8; ++j) b[j] = (__bf16)v[j];
    *(ushort4*)(dstb + 4 * lane)       = *(const ushort4*)(b);
    *(ushort4*)(dstb + 256 + 4 * lane) = *(const ushort4*)(b + 4);

    // fp8 e4m3 via HW packed convert (byte0=arg0, byte1=arg1; word1 = bytes 2,3)
    int p0 = 0, p1 = 0;
    p0 = __builtin_amdgcn_cvt_pk_fp8_f32(v[0], v[1], p0, false);
    p0 = __builtin_amdgcn_cvt_pk_fp8_f32(v[2], v[3], p0, true);
    p1 = __builtin_amdgcn_cvt_pk_fp8_f32(v[4], v[5], p1, false);
    p1 = __builtin_amdgcn_cvt_pk_fp8_f32(v[6], v[7], p1, true);
    *(int*)(dst8 + 4 * lane)       = p0;
    *(int*)(dst8 + 256 + 4 * lane) = p1;
}

// ---------------------------------------------------------------------------
// Kernel 2 (v6): fp8 GEMM, 256x256 tile, 8 waves (512 thr), BK=64, 3-deep
// LDS ring (96 KB), 4-phase interleave per K-tile (T3+T4+T5 — the regime
// where these are proven to pay; 2-phase variants all plateaued at ~44 us).
//   Phase p (kc=p>>1, mh=p&1): {8 ds_read_b64 (quadrant frags) | 1
//   global_load_lds of stage(t+2) into buf[(t+2)%3] | [p==3: vmcnt(4)]
//   | s_barrier | lgkmcnt(0)+sched_barrier | setprio(1) 16 MFMA setprio(0)
//   | s_barrier}.  vmcnt never drains to 0 until t=6.
//   Safety: double-barrier phases => all waves finished reading buf[(t+2)%3]
//   one full tile before any stage lands in it; per-tile vmcnt(4) before the
//   barrier publishes stage(t+1) to all waves before its first ds_read.
//   LDS layout/staging/reader swizzle = r8's harness-verified formulas:
//   64B rows packed 2/128B line; p8 = (((r&1)<<2)+c16)^((r>>1)&7).
//   Wave tile 128x64: acc[8][4] f32x4 (128 VGPR). launch_bounds(512,2)
//   caps VGPR at 256 (8 waves resident required).
// NOTE (r4): no mfma_scale 16x16x128 (VGPR spill catastrophe).
// NOTE (r5): no single-counter last-block-done fusion (cross-XCD serialize).
// ---------------------------------------------------------------------------
__global__ __launch_bounds__(512, 2) void main_kernel(
    const unsigned char* __restrict__ fn8, const unsigned char* __restrict__ wn8,
    float* __restrict__ es_p, unsigned* __restrict__ key_p)
{
    __shared__ __align__(16) unsigned char As[3][16384];
    __shared__ __align__(16) unsigned char Bs[3][16384];

    const int tid   = threadIdx.x;
    const int lane  = tid & 63;
    const int l15   = lane & 15;
    const int quad  = lane >> 4;
    const int wv    = tid >> 6;                  // 0..7
    const int wvM   = wv >> 2;                   // 0..1 (128-row halves)
    const int wvN   = wv & 3;                    // 0..3 (64-col quarters)
    const int xcd   = blockIdx.x & 7;
    const int j     = blockIdx.x >> 3;           // 0..63 within XCD
    const int mTile = xcd * 8 + (j >> 3);        // 0..63
    const int nTile = j & 7;                     // 0..7

    const unsigned char* fbase = fn8 + (size_t)mTile * 256 * EMB;
    const unsigned char* wbase = wn8 + (size_t)nTile * 256 * EMB;

    // staging lane geometry (r8-verified): slot = 16 rows x 64B = 1 KB
    const int r8   = lane >> 3;
    const int chv  = (lane & 7) ^ r8;
    const int gc16 = chv & 3;
    const int rowB = r8 * 2 + (chv >> 2);
    const int hoff = (quad & 1) << 3;

    f32x4 acc[8][4] = {};

    auto STAGE_A = [&](int t, int buf, int p) {
        const int slot = wv * 2 + p;              // 0..15
        const int grow = slot * 16 + rowB;        // 0..255
        const size_t goff = (size_t)grow * EMB + (size_t)t * 64 + (size_t)gc16 * 16;
        __builtin_amdgcn_global_load_lds(
            (const __attribute__((address_space(1))) void*)(fbase + goff),
            (__attribute__((address_space(3))) void*)(&As[buf][slot * 1024]), 16, 0, 0);
    };
    auto STAGE_B = [&](int t, int buf, int p) {
        const int slot = wv * 2 + p;
        const int grow = slot * 16 + rowB;
        const size_t goff = (size_t)grow * EMB + (size_t)t * 64 + (size_t)gc16 * 16;
        __builtin_amdgcn_global_load_lds(
            (const __attribute__((address_space(1))) void*)(wbase + goff),
            (__attribute__((address_space(3))) void*)(&Bs[buf][slot * 1024]), 16, 0, 0);
    };

    // prologue: tiles 0,1 in flight (8 loads/wave); drain tile 0 only
    STAGE_A(0, 0, 0); STAGE_A(0, 0, 1); STAGE_B(0, 0, 0); STAGE_B(0, 0, 1);
    STAGE_A(1, 1, 0); STAGE_A(1, 1, 1); STAGE_B(1, 1, 0); STAGE_B(1, 1, 1);
    asm volatile("s_waitcnt vmcnt(4)" ::: "memory");
    __builtin_amdgcn_s_barrier();

    #pragma unroll
    for (int t = 0; t < 8; ++t) {
        const int cur  = t % 3;
        const int nxt2 = (t + 2) % 3;
        #pragma unroll
        for (int p = 0; p < 4; ++p) {
            const int kc  = p >> 1;
            const int mh  = p & 1;
            const int c16 = kc * 2 + (quad >> 1);
            long aF[4], bF[4];
            #pragma unroll
            for (int i = 0; i < 4; ++i) {
                const int ar = wvM * 128 + (mh * 4 + i) * 16 + l15;
                const int br = wvN * 64 + i * 16 + l15;
                const int pa = ((((ar & 1) << 2) + c16) ^ ((ar >> 1) & 7)) * 16 + hoff;
                const int pb = ((((br & 1) << 2) + c16) ^ ((br >> 1) & 7)) * 16 + hoff;
                aF[i] = *(const long*)(&As[cur][(ar >> 1) * 128 + pa]);
                bF[i] = *(const long*)(&Bs[cur][(br >> 1) * 128 + pb]);
            }
            if (t < 6) {                          // 1 stage instr per phase
                if (p < 2) STAGE_A(t + 2, nxt2, p);
                else       STAGE_B(t + 2, nxt2, p - 2);
            }
            if (p == 3) {                         // once per tile, counted
                if (t < 6)       asm volatile("s_waitcnt vmcnt(4)" ::: "memory");
                else if (t == 6) asm volatile("s_waitcnt vmcnt(0)" ::: "memory");
            }
            __builtin_amdgcn_s_barrier();
            asm volatile("s_waitcnt lgkmcnt(0)" ::: "memory");
            __builtin_amdgcn_sched_barrier(0);
            __builtin_amdgcn_s_setprio(1);
            #pragma unroll
            for (int i = 0; i < 4; ++i)
                #pragma unroll
                for (int ni = 0; ni < 4; ++ni)
                    acc[mh * 4 + i][ni] = __builtin_amdgcn_mfma_f32_16x16x32_fp8_fp8(
                        aF[i], bF[ni], acc[mh * 4 + i][ni], 0, 0, 0);
            __builtin_amdgcn_s_setprio(0);
            __builtin_amdgcn_s_barrier();
        }
    }

    // Epilogue: es += exp2((v-1)*20*log2e); packed argmax; [row][32] partials.
    const float C20 = 28.853900817779268f;  // 20*log2(e)
    const int chunk = nTile * 4 + wvN;           // 64 cols per chunk
    #pragma unroll
    for (int mi = 0; mi < 8; ++mi) {
        float    es[4] = {0.f, 0.f, 0.f, 0.f};
        unsigned km[4] = {0u, 0u, 0u, 0u};
        #pragma unroll
        for (int ni = 0; ni < 4; ++ni) {
            const int col = nTile * 256 + wvN * 64 + ni * 16 + l15;
            const unsigned colenc = 2047u - (unsigned)col;
            const bool valid = (col < NC);
            #pragma unroll
            for (int r = 0; r < 4; ++r) {
                float v = valid ? acc[mi][ni][r] : -3.0f;
                es[r] += exp2f((v - 1.0f) * C20);
                unsigned u = __float_as_uint(v);
                unsigned k = u ^ (unsigned)(((int)u >> 31) | 0x80000000);
                unsigned pk = (k & 0xFFFFF800u) | colenc;  // bigger v, then smaller col
                km[r] = pk > km[r] ? pk : km[r];
            }
        }
        #pragma unroll
        for (int r = 0; r < 4; ++r) {
            #pragma unroll
            for (int m = 1; m < 16; m <<= 1) {
                es[r] += __shfl_xor(es[r], m, 64);
                unsigned x = __shfl_xor(km[r], m, 64);
                km[r] = x > km[r] ? x : km[r];
            }
        }
        if (l15 == 0) {
            #pragma unroll
            for (int r = 0; r < 4; ++r) {
                const int row = mTile * 256 + wvM * 128 + mi * 16 + quad * 4 + r;
                es_p [(size_t)row * NCHUNK + chunk] = es[r];
                key_p[(size_t)row * NCHUNK + chunk] = km[r];
            }
        }
    }
}

// ---------------------------------------------------------------------------
// Kernel 3 (v2): gather + finalize. One wave per row; interleaved reductions.
// ---------------------------------------------------------------------------
__global__ __launch_bounds__(256) void gather_fin_kernel(
    const __bf16* __restrict__ fnb, const __bf16* __restrict__ wnb,
    const int* __restrict__ label, const int* __restrict__ aux,
    const float* __restrict__ es_p, const unsigned* __restrict__ key_p,
    float* __restrict__ blkpart)
{
    const int lane = threadIdx.x & 63;
    const int wv   = threadIdx.x >> 6;
    const int row  = blockIdx.x * 4 + wv;

    // issue es/key partial loads early
    const int cch = lane & 31;
    float    es = es_p [(size_t)row * NCHUNK + cch];
    unsigned k  = key_p[(size_t)row * NCHUNK + cch];

    const int lab = label[row];
    int cols[6];
    cols[0] = lab;
    #pragma unroll
    for (int j = 0; j < NAUX; ++j) cols[j + 1] = aux[row * NAUX + j];

    bf16x8 f8 = *((const bf16x8*)fnb + (size_t)row * (EMB / 8) + lane);

    bf16x8 w8[6];
    #pragma unroll
    for (int c = 0; c < 6; ++c)
        w8[c] = *((const bf16x8*)wnb + (size_t)cols[c] * (EMB / 8) + lane);

    float fv[8];
    #pragma unroll
    for (int j = 0; j < 8; ++j) fv[j] = (float)f8[j];

    float d[6];
    #pragma unroll
    for (int c = 0; c < 6; ++c) {
        float t = 0.f;
        #pragma unroll
        for (int j = 0; j < 8; ++j) t += fv[j] * (float)w8[c][j];
        d[c] = t;
    }

    // interleaved reduction: 6 dot chains (+ es/key for the first 5 steps)
    #pragma unroll
    for (int m = 1; m < 64; m <<= 1) {
        #pragma unroll
        for (int c = 0; c < 6; ++c) d[c] += __shfl_xor(d[c], m, 64);
        if (m < 32) {
            es += __shfl_xor(es, m, 64);
            unsigned x = __shfl_xor(k, m, 64);
            k = x > k ? x : k;
        }
    }

    const float tgt  = d[0] * 20.0f;
    const float auxs = (d[1] + d[2] + d[3] + d[4] + d[5]) * 20.0f;
    const int amax = 2047 - (int)(k & 0x7FFu);
    const float loss = 20.0f + logf(es) - 0.95f * tgt - 0.01f * auxs;
    const float acc  = (amax == lab) ? 1.0f : 0.0f;

    __shared__ float sl[4], sa[4];
    if (lane == 0) { sl[wv] = loss; sa[wv] = acc; }
    __syncthreads();
    if (threadIdx.x == 0) {
        blkpart[blockIdx.x]        = sl[0] + sl[1] + sl[2] + sl[3];
        blkpart[GBLK + blockIdx.x] = sa[0] + sa[1] + sa[2] + sa[3];
    }
}

// ---------------------------------------------------------------------------
// Kernel 4: reduce 4096 block partials -> (loss, acc). One block.
// ---------------------------------------------------------------------------
__global__ __launch_bounds__(256) void fin2_kernel(
    const float* __restrict__ blkpart, float* __restrict__ out)
{
    float l = 0.f, a = 0.f;
    #pragma unroll
    for (int i = 0; i < GBLK / 256; ++i) {       // 16 iterations, unrolled:
        l += blkpart[i * 256 + threadIdx.x];     // all 32 loads in flight
        a += blkpart[GBLK + i * 256 + threadIdx.x];
    }
    #pragma unroll
    for (int m = 1; m < 64; m <<= 1) {
        l += __shfl_xor(l, m, 64);
        a += __shfl_xor(a, m, 64);
    }
    __shared__ float sl[4], sa[4];
    const int wv = threadIdx.x >> 6;
    if ((threadIdx.x & 63) == 0) { sl[wv] = l; sa[wv] = a; }
    __syncthreads();
    if (threadIdx.x == 0) {
        out[0] = (sl[0] + sl[1] + sl[2] + sl[3]) / (float)BS;
        out[1] = (sa[0] + sa[1] + sa[2] + sa[3]) / (float)BS;
    }
}

// ---------------------------------------------------------------------------
// Workspace layout (bytes):
//   fn8     @ 0         ( 8,388,608)  BS x 512 fp8
//   wn8     @ 8388608   ( 1,048,576)  NCP x 512 fp8 (pad rows zero)
//   fnb     @ 9437184   (16,777,216)  BS x 512 bf16
//   wnb     @ 26214400  ( 2,097,152)  NCP x 512 bf16 (pad rows zero)
//   es_p    @ 28311552  ( 2,097,152)  [BS][32] f32
//   key_p   @ 30408704  ( 2,097,152)  [BS][32] u32
//   blkpart @ 32505856  (    32,768)  [2][4096] f32
// ---------------------------------------------------------------------------
extern "C" void kernel_launch(void* const* d_in, const int* in_sizes, int n_in,
                              void* d_out, int out_size, void* d_ws, size_t ws_size,
                              hipStream_t stream)
{
    const float* feat  = (const float*)d_in[0];
    const float* wemb  = (const float*)d_in[1];
    const int*   label = (const int*)d_in[2];
    const int*   aux   = (const int*)d_in[3];

    char* ws = (char*)d_ws;
    unsigned char* fn8     = (unsigned char*)(ws);
    unsigned char* wn8     = (unsigned char*)(ws + 8388608);
    __bf16*        fnb     = (__bf16*)(ws + 9437184);
    __bf16*        wnb     = (__bf16*)(ws + 26214400);
    float*         es_p    = (float*)(ws + 28311552);
    unsigned*      key_p   = (unsigned*)(ws + 30408704);
    float*         blkpart = (float*)(ws + 32505856);
    float*         out     = (float*)d_out;

    hipLaunchKernelGGL(norm_kernel, dim3((BS + NCP) / 4), dim3(256), 0, stream,
                       feat, wemb, fn8, wn8, fnb, wnb);
    hipLaunchKernelGGL(main_kernel, dim3((BS / 256) * (NCP / 256)), dim3(512), 0, stream,
                       fn8, wn8, es_p, key_p);
    hipLaunchKernelGGL(gather_fin_kernel, dim3(GBLK), dim3(256), 0, stream,
                       fnb, wnb, label, aux, es_p, key_p, blkpart);
    hipLaunchKernelGGL(fin2_kernel, dim3(1), dim3(256), 0, stream, blkpart, out);
}

// Round 10
// 131.792 us; speedup vs baseline: 1.1062x; 1.1062x over previous
//
#include <hip/hip_runtime.h>
#include <hip/hip_bf16.h>
#include <hip/hip_fp8.h>
#include <stdint.h>

#define BS   16384
#define NC   2000
#define NCP  2048            // padded N (wn zero-filled rows 2000..2047)
#define EMB  512
#define NAUX 5
#define NCHUNK 32            // partial chunks per row: nTile*2 + wvN
#define GBLK 4096            // gather_fin blocks (4 rows each)

typedef __bf16 bf16x8 __attribute__((ext_vector_type(8)));
typedef float  f32x4  __attribute__((ext_vector_type(4)));

// ---------------------------------------------------------------------------
// Kernel 1 (v2): row-normalize; one WAVE per row, fully coalesced.
// ---------------------------------------------------------------------------
__global__ __launch_bounds__(256) void norm_kernel(
    const float* __restrict__ feat, const float* __restrict__ wemb,
    unsigned char* __restrict__ fn8, unsigned char* __restrict__ wn8,
    __bf16* __restrict__ fnb, __bf16* __restrict__ wnb)
{
    const int lane = threadIdx.x & 63;
    const int wv   = threadIdx.x >> 6;
    const int row  = blockIdx.x * 4 + wv;        // 0..18431

    if (row >= BS + NC) {                        // pad rows -> zeros
        const int pr = row - BS;
        *(unsigned*)(wn8 + (size_t)pr * EMB + lane * 4)       = 0u;
        *(unsigned*)(wn8 + (size_t)pr * EMB + 256 + lane * 4) = 0u;
        ushort4 z = {0, 0, 0, 0};
        ((ushort4*)(wnb + (size_t)pr * EMB))[lane]      = z;
        ((ushort4*)(wnb + (size_t)pr * EMB))[64 + lane] = z;
        return;
    }
    const float* src;
    unsigned char* dst8;
    __bf16* dstb;
    if (row < BS) { src = feat + (size_t)row * EMB;
                    dst8 = fn8 + (size_t)row * EMB;        dstb = fnb + (size_t)row * EMB; }
    else          { src = wemb + (size_t)(row - BS) * EMB;
                    dst8 = wn8 + (size_t)(row - BS) * EMB; dstb = wnb + (size_t)(row - BS) * EMB; }

    const float4* s4 = (const float4*)src;
    float4 x = s4[lane];                         // cols 4*lane   .. +3
    float4 y = s4[64 + lane];                    // cols 256+4*lane .. +3

    float ss = x.x * x.x + x.y * x.y + x.z * x.z + x.w * x.w
             + y.x * y.x + y.y * y.y + y.z * y.z + y.w * y.w;
    #pragma unroll
    for (int m = 1; m < 64; m <<= 1) ss += __shfl_xor(ss, m, 64);
    const float scale = 1.0f / fmaxf(sqrtf(ss), 1e-12f);

    float v[8];
    v[0] = x.x * scale; v[1] = x.y * scale; v[2] = x.z * scale; v[3] = x.w * scale;
    v[4] = y.x * scale; v[5] = y.y * scale; v[6] = y.z * scale; v[7] = y.w * scale;

    // bf16 copy (two 8 B coalesced stores)
    __bf16 b[8];
    #pragma unroll
    for (int j = 0; j < 8; ++j) b[j] = (__bf16)v[j];
    *(ushort4*)(dstb + 4 * lane)       = *(const ushort4*)(b);
    *(ushort4*)(dstb + 256 + 4 * lane) = *(const ushort4*)(b + 4);

    // fp8 e4m3 via HW packed convert (byte0=arg0, byte1=arg1; word1 = bytes 2,3)
    int p0 = 0, p1 = 0;
    p0 = __builtin_amdgcn_cvt_pk_fp8_f32(v[0], v[1], p0, false);
    p0 = __builtin_amdgcn_cvt_pk_fp8_f32(v[2], v[3], p0, true);
    p1 = __builtin_amdgcn_cvt_pk_fp8_f32(v[4], v[5], p1, false);
    p1 = __builtin_amdgcn_cvt_pk_fp8_f32(v[6], v[7], p1, true);
    *(int*)(dst8 + 4 * lane)       = p0;
    *(int*)(dst8 + 256 + 4 * lane) = p1;
}

// ---------------------------------------------------------------------------
// Kernel 2 (v3): fp8 GEMM, BK=128 SINGLE-buffered, 32 KB LDS -> 4-5 blocks/CU
// (m97-proven regime: cross-BLOCK overlap hides the per-step drain). 88 VGPR.
//   128x128 tile, 4 waves 2x2; A,B tiles 128x128 fp8 = 16 KB each.
//   4 K-steps: {sync; stage(global_load_lds w=16); vmcnt(0); sync; 64 MFMA}.
//   16B-chunk XOR swizzle via pre-swizzled global source (chunk ^ (row&7));
//   frag reads ds_read_b64 at chunk (kc*2+(quad>>1))^(row&7), half = quad&1.
//   XCD swizzle: xcd=bid&7 owns 16 mTiles (L2 locality, FETCH stays ~8.3MB).
// mfma_f32_16x16x32_fp8_fp8 layouts (same geometry as verified bf16 16x16x32):
//   A frag: lane(m=lane&15, q=lane>>4) holds A[m][q*8+j], 8 fp8 = 8 B (long)
//   B frag: lane(n=lane&15, q)         holds B[q*8+j][n] = wn[n][q*8+j]
//   C/D:    col(n) = lane&15, row(m) = q*4 + reg   [dtype-independent]
// NOTE (r4): no mfma_scale 16x16x128 (VGPR=64 + scratch spill catastrophe).
// NOTE (r5): no single-counter last-block-done fusion (cross-XCD serialize).
// NOTE (r8): counted-vmcnt BK=64 double-buffer = neutral (44 us plateau).
// NOTE (r9): 256^2 8-wave 4-phase ring = REGRESSION (56 us): 96KB LDS ->
//   1 block/CU, and K=512 gives only 8 K-tiles — too short to amortize a
//   deep-pipeline schedule (its wins are measured at K>=4096).
// ---------------------------------------------------------------------------
__global__ __launch_bounds__(256) void main_kernel(
    const unsigned char* __restrict__ fn8, const unsigned char* __restrict__ wn8,
    float* __restrict__ es_p, unsigned* __restrict__ key_p)
{
    __shared__ __align__(16) unsigned char As[128 * 128];
    __shared__ __align__(16) unsigned char Bs[128 * 128];

    const int tid   = threadIdx.x;
    const int lane  = tid & 63;
    const int l15   = lane & 15;
    const int quad  = lane >> 4;
    const int wv    = tid >> 6;
    const int wvM   = wv >> 1;
    const int wvN   = wv & 1;
    const int xcd   = blockIdx.x & 7;
    const int j     = blockIdx.x >> 3;           // 0..255 within XCD
    const int mTile = xcd * 16 + (j >> 4);       // 0..127
    const int nTile = j & 15;                    // 0..15

    const unsigned char* fbase = fn8 + (size_t)mTile * 128 * EMB;
    const unsigned char* wbase = wn8 + (size_t)nTile * 128 * EMB;

    // Staging geometry: one global_load_lds = 64 lanes x 16 B = 8 rows x 128 B.
    // Lane L covers row slot*8 + (L>>3), phys 16B chunk L&7 (linear LDS dest);
    // logical chunk = phys ^ (row&7), applied on the per-lane GLOBAL address.
    const int rIn8 = lane >> 3;                   // row within 8-row slot
    const int cLog = (lane & 7) ^ rIn8;           // row&7 == rIn8 by construction

    f32x4 acc[4][4] = {};

    #pragma unroll
    for (int t = 0; t < 4; ++t) {
        __syncthreads();                          // previous step's readers done
        #pragma unroll
        for (int p = 0; p < 4; ++p) {
            const int slot = wv * 4 + p;          // 0..15 -> rows slot*8..+8
            const int row  = slot * 8 + rIn8;
            const size_t goff = (size_t)row * EMB + (size_t)t * 128 + (size_t)cLog * 16;
            __builtin_amdgcn_global_load_lds(
                (const __attribute__((address_space(1))) void*)(fbase + goff),
                (__attribute__((address_space(3))) void*)(As + slot * 1024), 16, 0, 0);
            __builtin_amdgcn_global_load_lds(
                (const __attribute__((address_space(1))) void*)(wbase + goff),
                (__attribute__((address_space(3))) void*)(Bs + slot * 1024), 16, 0, 0);
        }
        __builtin_amdgcn_s_waitcnt(0);            // drain global->LDS DMA
        __syncthreads();                          // staged tile visible to all

        #pragma unroll
        for (int kc = 0; kc < 4; ++kc) {
            long aF[4], bF[4];
            const int c16  = kc * 2 + (quad >> 1);
            const int hoff = (quad & 1) << 3;
            #pragma unroll
            for (int i = 0; i < 4; ++i) {
                const int ar = wvM * 64 + i * 16 + l15;
                const int br = wvN * 64 + i * 16 + l15;
                const int ca = ((c16 ^ (l15 & 7)) << 4) + hoff;
                aF[i] = *(const long*)(As + ar * 128 + ca);
                bF[i] = *(const long*)(Bs + br * 128 + ca);
            }
            #pragma unroll
            for (int mi = 0; mi < 4; ++mi)
                #pragma unroll
                for (int ni = 0; ni < 4; ++ni)
                    acc[mi][ni] = __builtin_amdgcn_mfma_f32_16x16x32_fp8_fp8(
                        aF[mi], bF[ni], acc[mi][ni], 0, 0, 0);
        }
    }

    // Epilogue: es += exp2((v-1)*20*log2e); packed argmax; [row][32] partials.
    const float C20 = 28.853900817779268f;  // 20*log2(e)
    const int chunk = nTile * 2 + wvN;
    #pragma unroll
    for (int mi = 0; mi < 4; ++mi) {
        float    es[4] = {0.f, 0.f, 0.f, 0.f};
        unsigned km[4] = {0u, 0u, 0u, 0u};
        #pragma unroll
        for (int ni = 0; ni < 4; ++ni) {
            const int col = nTile * 128 + wvN * 64 + ni * 16 + l15;
            const unsigned colenc = 2047u - (unsigned)col;
            const bool valid = (col < NC);
            #pragma unroll
            for (int r = 0; r < 4; ++r) {
                float v = valid ? acc[mi][ni][r] : -3.0f;
                es[r] += exp2f((v - 1.0f) * C20);
                unsigned u = __float_as_uint(v);
                unsigned k = u ^ (unsigned)(((int)u >> 31) | 0x80000000);
                unsigned pk = (k & 0xFFFFF800u) | colenc;  // bigger v, then smaller col
                km[r] = pk > km[r] ? pk : km[r];
            }
        }
        #pragma unroll
        for (int r = 0; r < 4; ++r) {
            #pragma unroll
            for (int m = 1; m < 16; m <<= 1) {
                es[r] += __shfl_xor(es[r], m, 64);
                unsigned x = __shfl_xor(km[r], m, 64);
                km[r] = x > km[r] ? x : km[r];
            }
        }
        if (l15 == 0) {
            #pragma unroll
            for (int r = 0; r < 4; ++r) {
                const int row = mTile * 128 + wvM * 64 + mi * 16 + quad * 4 + r;
                es_p [(size_t)row * NCHUNK + chunk] = es[r];
                key_p[(size_t)row * NCHUNK + chunk] = km[r];
            }
        }
    }
}

// ---------------------------------------------------------------------------
// Kernel 3 (v2): gather + finalize. One wave per row; interleaved reductions.
// ---------------------------------------------------------------------------
__global__ __launch_bounds__(256) void gather_fin_kernel(
    const __bf16* __restrict__ fnb, const __bf16* __restrict__ wnb,
    const int* __restrict__ label, const int* __restrict__ aux,
    const float* __restrict__ es_p, const unsigned* __restrict__ key_p,
    float* __restrict__ blkpart)
{
    const int lane = threadIdx.x & 63;
    const int wv   = threadIdx.x >> 6;
    const int row  = blockIdx.x * 4 + wv;

    // issue es/key partial loads early
    const int cch = lane & 31;
    float    es = es_p [(size_t)row * NCHUNK + cch];
    unsigned k  = key_p[(size_t)row * NCHUNK + cch];

    const int lab = label[row];
    int cols[6];
    cols[0] = lab;
    #pragma unroll
    for (int j = 0; j < NAUX; ++j) cols[j + 1] = aux[row * NAUX + j];

    bf16x8 f8 = *((const bf16x8*)fnb + (size_t)row * (EMB / 8) + lane);

    bf16x8 w8[6];
    #pragma unroll
    for (int c = 0; c < 6; ++c)
        w8[c] = *((const bf16x8*)wnb + (size_t)cols[c] * (EMB / 8) + lane);

    float fv[8];
    #pragma unroll
    for (int j = 0; j < 8; ++j) fv[j] = (float)f8[j];

    float d[6];
    #pragma unroll
    for (int c = 0; c < 6; ++c) {
        float t = 0.f;
        #pragma unroll
        for (int j = 0; j < 8; ++j) t += fv[j] * (float)w8[c][j];
        d[c] = t;
    }

    // interleaved reduction: 6 dot chains (+ es/key for the first 5 steps)
    #pragma unroll
    for (int m = 1; m < 64; m <<= 1) {
        #pragma unroll
        for (int c = 0; c < 6; ++c) d[c] += __shfl_xor(d[c], m, 64);
        if (m < 32) {
            es += __shfl_xor(es, m, 64);
            unsigned x = __shfl_xor(k, m, 64);
            k = x > k ? x : k;
        }
    }

    const float tgt  = d[0] * 20.0f;
    const float auxs = (d[1] + d[2] + d[3] + d[4] + d[5]) * 20.0f;
    const int amax = 2047 - (int)(k & 0x7FFu);
    const float loss = 20.0f + logf(es) - 0.95f * tgt - 0.01f * auxs;
    const float acc  = (amax == lab) ? 1.0f : 0.0f;

    __shared__ float sl[4], sa[4];
    if (lane == 0) { sl[wv] = loss; sa[wv] = acc; }
    __syncthreads();
    if (threadIdx.x == 0) {
        blkpart[blockIdx.x]        = sl[0] + sl[1] + sl[2] + sl[3];
        blkpart[GBLK + blockIdx.x] = sa[0] + sa[1] + sa[2] + sa[3];
    }
}

// ---------------------------------------------------------------------------
// Kernel 4: reduce 4096 block partials -> (loss, acc). One block.
// ---------------------------------------------------------------------------
__global__ __launch_bounds__(256) void fin2_kernel(
    const float* __restrict__ blkpart, float* __restrict__ out)
{
    float l = 0.f, a = 0.f;
    #pragma unroll
    for (int i = 0; i < GBLK / 256; ++i) {       // 16 iterations, unrolled:
        l += blkpart[i * 256 + threadIdx.x];     // all 32 loads in flight
        a += blkpart[GBLK + i * 256 + threadIdx.x];
    }
    #pragma unroll
    for (int m = 1; m < 64; m <<= 1) {
        l += __shfl_xor(l, m, 64);
        a += __shfl_xor(a, m, 64);
    }
    __shared__ float sl[4], sa[4];
    const int wv = threadIdx.x >> 6;
    if ((threadIdx.x & 63) == 0) { sl[wv] = l; sa[wv] = a; }
    __syncthreads();
    if (threadIdx.x == 0) {
        out[0] = (sl[0] + sl[1] + sl[2] + sl[3]) / (float)BS;
        out[1] = (sa[0] + sa[1] + sa[2] + sa[3]) / (float)BS;
    }
}

// ---------------------------------------------------------------------------
// Workspace layout (bytes):
//   fn8     @ 0         ( 8,388,608)  BS x 512 fp8
//   wn8     @ 8388608   ( 1,048,576)  NCP x 512 fp8 (pad rows zero)
//   fnb     @ 9437184   (16,777,216)  BS x 512 bf16
//   wnb     @ 26214400  ( 2,097,152)  NCP x 512 bf16 (pad rows zero)
//   es_p    @ 28311552  ( 2,097,152)  [BS][32] f32
//   key_p   @ 30408704  ( 2,097,152)  [BS][32] u32
//   blkpart @ 32505856  (    32,768)  [2][4096] f32
// ---------------------------------------------------------------------------
extern "C" void kernel_launch(void* const* d_in, const int* in_sizes, int n_in,
                              void* d_out, int out_size, void* d_ws, size_t ws_size,
                              hipStream_t stream)
{
    const float* feat  = (const float*)d_in[0];
    const float* wemb  = (const float*)d_in[1];
    const int*   label = (const int*)d_in[2];
    const int*   aux   = (const int*)d_in[3];

    char* ws = (char*)d_ws;
    unsigned char* fn8     = (unsigned char*)(ws);
    unsigned char* wn8     = (unsigned char*)(ws + 8388608);
    __bf16*        fnb     = (__bf16*)(ws + 9437184);
    __bf16*        wnb     = (__bf16*)(ws + 26214400);
    float*         es_p    = (float*)(ws + 28311552);
    unsigned*      key_p   = (unsigned*)(ws + 30408704);
    float*         blkpart = (float*)(ws + 32505856);
    float*         out     = (float*)d_out;

    hipLaunchKernelGGL(norm_kernel, dim3((BS + NCP) / 4), dim3(256), 0, stream,
                       feat, wemb, fn8, wn8, fnb, wnb);
    hipLaunchKernelGGL(main_kernel, dim3((BS / 128) * (NCP / 128)), dim3(256), 0, stream,
                       fn8, wn8, es_p, key_p);
    hipLaunchKernelGGL(gather_fin_kernel, dim3(GBLK), dim3(256), 0, stream,
                       fnb, wnb, label, aux, es_p, key_p, blkpart);
    hipLaunchKernelGGL(fin2_kernel, dim3(1), dim3(256), 0, stream, blkpart, out);
}